// Round 9
// baseline (3257.618 us; speedup 1.0000x reference)
//
#include <hip/hip_runtime.h>
#include <cstddef>

#define NB 32      // batch
#define NP 196     // pixels
#define NE 2048    // encoder dim
#define ND 512     // decoder/att/emb dim
#define NV 32000   // vocab
#define NL 21
#define NT 20      // decode steps

// ---------------- setup ----------------

__global__ void k_sort(const int* __restrict__ lens, int* __restrict__ sind, int* __restrict__ dlens,
                       int* __restrict__ rowmap, int* __restrict__ mpad)
{
    int i = threadIdx.x;
    if (i < NB) {
        int li = lens[i];
        int r = 0;
        for (int j = 0; j < NB; ++j) {
            int lj = lens[j];
            if (lj > li || (lj == li && j < i)) ++r;
        }
        sind[r] = i;
        dlens[r] = li - 1;
    }
    __syncthreads();
    if (i == 0) {
        int c = 0;
        for (int t = 0; t < NT; ++t)
            for (int b = 0; b < NB; ++b)
                if (t < dlens[b]) rowmap[c++] = t * NB + b;
        int pad = (c + 63) & ~63;
        for (int r = c; r < pad; ++r) rowmap[r] = -1;
        mpad[0] = pad;
    }
}

__global__ __launch_bounds__(256) void k_mean(const float* __restrict__ enc, const int* __restrict__ sind,
                                              float* __restrict__ mean_enc)
{
    int b = blockIdx.y;
    int k = blockIdx.x * 256 + threadIdx.x;
    const float* e = enc + (size_t)sind[b] * NP * NE + k;
    float s0 = 0.f, s1 = 0.f, s2 = 0.f, s3 = 0.f;
    for (int p = 0; p < NP; p += 4) {
        s0 += e[(size_t)(p + 0) * NE];
        s1 += e[(size_t)(p + 1) * NE];
        s2 += e[(size_t)(p + 2) * NE];
        s3 += e[(size_t)(p + 3) * NE];
    }
    mean_enc[(size_t)b * NE + k] = (s0 + s1 + s2 + s3) * (1.0f / NP);
}

__global__ __launch_bounds__(256) void k_zero(const int* __restrict__ dlens, float* __restrict__ out)
{
    int b = blockIdx.x / NT, t = blockIdx.x % NT;
    if (t < dlens[b]) return;
    float4 z = {0.f, 0.f, 0.f, 0.f};
    float4* row = (float4*)(out + ((size_t)b * NT + t) * NV);
    for (int i = threadIdx.x; i < NV / 4; i += 256) row[i] = z;
}

// ---------------- skinny GEMM: h0/c0 into hcbuf[0]; seeds xh h-part ----------------
__global__ __launch_bounds__(256) void gemm_skinny(
    const float* __restrict__ A0, const float* __restrict__ W0a, const float* __restrict__ W0b,
    const float* __restrict__ ba, const float* __restrict__ bb,
    float* __restrict__ C, float* __restrict__ xh)
{
    __shared__ float As[32][32];
    __shared__ float Ws[64][33];
    int n0 = blockIdx.x * 64;
    int tid = threadIdx.x;
    int lb = tid / 8, lkq = tid % 8;
    int b4 = (tid / 32) * 4, nl = (tid % 32) * 2;
    float acc[4][2] = {};
    for (int kt = 0; kt < NE; kt += 32) {
        float4 a4 = *reinterpret_cast<const float4*>(A0 + (size_t)lb * NE + kt + lkq * 4);
        As[lkq * 4 + 0][lb] = a4.x; As[lkq * 4 + 1][lb] = a4.y;
        As[lkq * 4 + 2][lb] = a4.z; As[lkq * 4 + 3][lb] = a4.w;
        #pragma unroll
        for (int r = 0; r < 2; ++r) {
            int s = tid + r * 256;
            int n_l = s / 8, kq = s % 8;
            int ng = n0 + n_l;
            const float* wrow = (ng < 512) ? (W0a + (size_t)ng * NE)
                                           : (W0b + (size_t)(ng - 512) * NE);
            float4 w4 = *reinterpret_cast<const float4*>(wrow + kt + kq * 4);
            Ws[n_l][kq * 4 + 0] = w4.x; Ws[n_l][kq * 4 + 1] = w4.y;
            Ws[n_l][kq * 4 + 2] = w4.z; Ws[n_l][kq * 4 + 3] = w4.w;
        }
        __syncthreads();
        #pragma unroll
        for (int k = 0; k < 32; ++k) {
            float4 av = *reinterpret_cast<const float4*>(&As[k][b4]);
            float w0 = Ws[nl][k], w1 = Ws[nl + 1][k];
            acc[0][0] += av.x * w0; acc[0][1] += av.x * w1;
            acc[1][0] += av.y * w0; acc[1][1] += av.y * w1;
            acc[2][0] += av.z * w0; acc[2][1] += av.z * w1;
            acc[3][0] += av.w * w0; acc[3][1] += av.w * w1;
        }
        __syncthreads();
    }
    #pragma unroll
    for (int j = 0; j < 2; ++j) {
        int ng = n0 + nl + j;
        float bias = (ng < 512) ? ba[ng] : bb[ng - 512];
        #pragma unroll
        for (int i = 0; i < 4; ++i) {
            float v = acc[i][j] + bias;
            int b = b4 + i;
            C[(size_t)b * 1024 + ng] = v;
            if (ng < 512) xh[(size_t)b * 3072 + 2560 + ng] = v;
        }
    }
}

// ---------------- att1 GEMM: BM=64 BN=64, XCD-swizzled so A-panel stays on one XCD ----------------
// fid -> (c=fid&7, x=(fid>>3)&7, pg=fid>>6); p = pg*8+c. Same-p blocks differ by 8 in fid
// -> same XCD under round-robin. Grid 832 flat (48 idle).
__global__ __launch_bounds__(256) void gemm_att1(
    const float* __restrict__ A, const float* __restrict__ W, const float* __restrict__ bias,
    float* __restrict__ C, const int* __restrict__ sind)
{
    int fid = blockIdx.x;
    int c = fid & 7, x = (fid >> 3) & 7, pg = fid >> 6;
    int p = pg * 8 + c;
    if (p >= 98) return;
    int bm0 = p * 64, bn0 = x * 64;
    __shared__ float As[16][64];
    __shared__ float Ws[16][64];
    int tid = threadIdx.x;
    int ty = tid / 16, tx = tid % 16;
    int lm = tid / 4, lk = (tid % 4) * 4;
    int mg = bm0 + lm;
    int bidx = mg / NP, pp = mg - bidx * NP;
    const float* arow = A + ((size_t)sind[bidx] * NP + pp) * (size_t)NE;
    const float* wrow = W + (size_t)(bn0 + lm) * NE;
    float acc[4][4] = {};
    for (int kt = 0; kt < NE; kt += 16) {
        float4 a4 = *reinterpret_cast<const float4*>(arow + kt + lk);
        float4 w4 = *reinterpret_cast<const float4*>(wrow + kt + lk);
        As[lk + 0][lm] = a4.x; As[lk + 1][lm] = a4.y; As[lk + 2][lm] = a4.z; As[lk + 3][lm] = a4.w;
        Ws[lk + 0][lm] = w4.x; Ws[lk + 1][lm] = w4.y; Ws[lk + 2][lm] = w4.z; Ws[lk + 3][lm] = w4.w;
        __syncthreads();
        #pragma unroll
        for (int k = 0; k < 16; ++k) {
            float4 av = *reinterpret_cast<const float4*>(&As[k][ty * 4]);
            float4 wv = *reinterpret_cast<const float4*>(&Ws[k][tx * 4]);
            acc[0][0] += av.x * wv.x; acc[0][1] += av.x * wv.y; acc[0][2] += av.x * wv.z; acc[0][3] += av.x * wv.w;
            acc[1][0] += av.y * wv.x; acc[1][1] += av.y * wv.y; acc[1][2] += av.y * wv.z; acc[1][3] += av.y * wv.w;
            acc[2][0] += av.z * wv.x; acc[2][1] += av.z * wv.y; acc[2][2] += av.z * wv.z; acc[2][3] += av.z * wv.w;
            acc[3][0] += av.w * wv.x; acc[3][1] += av.w * wv.y; acc[3][2] += av.w * wv.z; acc[3][3] += av.w * wv.w;
        }
        __syncthreads();
    }
    #pragma unroll
    for (int i = 0; i < 4; ++i) {
        int m = bm0 + ty * 4 + i;
        int n = bn0 + tx * 4;
        float4 o;
        o.x = acc[i][0] + bias[n + 0];
        o.y = acc[i][1] + bias[n + 1];
        o.z = acc[i][2] + bias[n + 2];
        o.w = acc[i][3] + bias[n + 3];
        *reinterpret_cast<float4*>(C + (size_t)m * ND + n) = o;
    }
}

// ---------------- preds GEMM: BM=64 BN=128, live rows only ----------------
__global__ __launch_bounds__(256) void gemm_preds(
    const float* __restrict__ A, const float* __restrict__ W, const float* __restrict__ bias,
    float* __restrict__ C, const int* __restrict__ rowmap, const int* __restrict__ mpad)
{
    int bm0 = blockIdx.x * 64;
    if (bm0 >= mpad[0]) return;
    int bn0 = blockIdx.y * 128;
    __shared__ float As[16][64];
    __shared__ float Ws[16][128];
    int tid = threadIdx.x;
    int ty = tid / 32, tx = tid % 32;
    int lm = tid / 4, lk = (tid % 4) * 4;
    int rid = rowmap[bm0 + lm];
    const float* arow = A + (size_t)(rid < 0 ? 0 : rid) * ND;
    const float* wrow0 = W + (size_t)(bn0 + lm) * ND;
    const float* wrow1 = W + (size_t)(bn0 + 64 + lm) * ND;
    float4 bias4 = *reinterpret_cast<const float4*>(bias + bn0 + tx * 4);
    float acc[8][4] = {};
    for (int kt = 0; kt < ND; kt += 16) {
        float4 a4 = *reinterpret_cast<const float4*>(arow + kt + lk);
        float4 w0 = *reinterpret_cast<const float4*>(wrow0 + kt + lk);
        float4 w1 = *reinterpret_cast<const float4*>(wrow1 + kt + lk);
        As[lk + 0][lm] = a4.x; As[lk + 1][lm] = a4.y; As[lk + 2][lm] = a4.z; As[lk + 3][lm] = a4.w;
        Ws[lk + 0][lm] = w0.x; Ws[lk + 1][lm] = w0.y; Ws[lk + 2][lm] = w0.z; Ws[lk + 3][lm] = w0.w;
        Ws[lk + 0][64 + lm] = w1.x; Ws[lk + 1][64 + lm] = w1.y; Ws[lk + 2][64 + lm] = w1.z; Ws[lk + 3][64 + lm] = w1.w;
        __syncthreads();
        #pragma unroll
        for (int k = 0; k < 16; ++k) {
            float4 av0 = *reinterpret_cast<const float4*>(&As[k][ty * 8]);
            float4 av1 = *reinterpret_cast<const float4*>(&As[k][ty * 8 + 4]);
            float4 wv = *reinterpret_cast<const float4*>(&Ws[k][tx * 4]);
            acc[0][0] += av0.x * wv.x; acc[0][1] += av0.x * wv.y; acc[0][2] += av0.x * wv.z; acc[0][3] += av0.x * wv.w;
            acc[1][0] += av0.y * wv.x; acc[1][1] += av0.y * wv.y; acc[1][2] += av0.y * wv.z; acc[1][3] += av0.y * wv.w;
            acc[2][0] += av0.z * wv.x; acc[2][1] += av0.z * wv.y; acc[2][2] += av0.z * wv.z; acc[2][3] += av0.z * wv.w;
            acc[3][0] += av0.w * wv.x; acc[3][1] += av0.w * wv.y; acc[3][2] += av0.w * wv.z; acc[3][3] += av0.w * wv.w;
            acc[4][0] += av1.x * wv.x; acc[4][1] += av1.x * wv.y; acc[4][2] += av1.x * wv.z; acc[4][3] += av1.x * wv.w;
            acc[5][0] += av1.y * wv.x; acc[5][1] += av1.y * wv.y; acc[5][2] += av1.y * wv.z; acc[5][3] += av1.y * wv.w;
            acc[6][0] += av1.z * wv.x; acc[6][1] += av1.z * wv.y; acc[6][2] += av1.z * wv.z; acc[6][3] += av1.z * wv.w;
            acc[7][0] += av1.w * wv.x; acc[7][1] += av1.w * wv.y; acc[7][2] += av1.w * wv.z; acc[7][3] += av1.w * wv.w;
        }
        __syncthreads();
    }
    #pragma unroll
    for (int i = 0; i < 8; ++i) {
        int rm = rowmap[bm0 + ty * 8 + i];
        if (rm < 0) continue;
        int t = rm / NB, b = rm % NB;
        float4 o;
        o.x = acc[i][0] + bias4.x; o.y = acc[i][1] + bias4.y;
        o.z = acc[i][2] + bias4.z; o.w = acc[i][3] + bias4.w;
        *reinterpret_cast<float4*>(C + ((size_t)b * NT + t) * NV + bn0 + tx * 4) = o;
    }
}

// ---------------- kA: fused cell(t-1) + attg GEMM (40 blocks) ----------------
// Phase 1: every block redundantly finalizes the LSTM cell of step t-1 into LDS heffT
// (padded transpose [512][33]); block 0 commits state to hcbuf[t&1] (double-buffered,
// read parity (t-1)&1 != write parity -> no race), hseq[t-1], xh h-part.
// Phase 2: attg[32][2560] = heff @ [W_da;W_fb]^T + [b_da;b_fb], A read from LDS.
__global__ __launch_bounds__(256) void kA(
    const float* __restrict__ gpart, const int* __restrict__ dlens,
    const float* __restrict__ W_da, const float* __restrict__ W_fb,
    const float* __restrict__ b_da, const float* __restrict__ b_fb,
    const float* __restrict__ b_ih, const float* __restrict__ b_hh,
    float* __restrict__ hcbuf, float* __restrict__ attg,
    float* __restrict__ hseq, float* __restrict__ xh, int t)
{
    __shared__ float heffT[512 * 33];
    __shared__ float Ws[64][33];
    int tid = threadIdx.x;
    const float* hcR = hcbuf + (size_t)((t > 0 ? (t - 1) : 0) & 1) * NB * 1024;
    if (t == 0) {
        for (int i = 0; i < 64; ++i) {
            int idx = i * 256 + tid, b = idx >> 9, d = idx & 511;
            heffT[d * 33 + b] = hcR[(size_t)b * 1024 + d];
        }
    } else {
        float* hcW = hcbuf + (size_t)(t & 1) * NB * 1024;
        bool blk0 = (blockIdx.x == 0);
        for (int i = 0; i < 64; ++i) {
            int idx = i * 256 + tid, b = idx >> 9, d = idx & 511;
            float g0 = b_ih[d] + b_hh[d];
            float g1 = b_ih[512 + d] + b_hh[512 + d];
            float g2 = b_ih[1024 + d] + b_hh[1024 + d];
            float g3 = b_ih[1536 + d] + b_hh[1536 + d];
            #pragma unroll
            for (int ks = 0; ks < 4; ++ks) {
                const float* gp = gpart + ((size_t)ks * NB + b) * 2048;
                g0 += gp[d]; g1 += gp[512 + d]; g2 += gp[1024 + d]; g3 += gp[1536 + d];
            }
            float ig = 1.f / (1.f + expf(-g0));
            float fg = 1.f / (1.f + expf(-g1));
            float gt = tanhf(g2);
            float og = 1.f / (1.f + expf(-g3));
            float h_old = hcR[(size_t)b * 1024 + d];
            float c_old = hcR[(size_t)b * 1024 + 512 + d];
            float c_new = fg * c_old + ig * gt;
            float h_new = og * tanhf(c_new);
            bool live = (t - 1) < dlens[b];
            float hv = live ? h_new : h_old;
            float cv = live ? c_new : c_old;
            heffT[d * 33 + b] = hv;
            if (blk0) {
                hcW[(size_t)b * 1024 + d] = hv;
                hcW[(size_t)b * 1024 + 512 + d] = cv;
                hseq[((size_t)(t - 1) * NB + b) * ND + d] = h_new;
                xh[(size_t)b * 3072 + 2560 + d] = hv;
            }
        }
    }
    __syncthreads();

    int n0 = blockIdx.x * 64;
    int b4 = (tid / 32) * 4, nl = (tid % 32) * 2;
    float acc[4][2] = {};
    for (int kt = 0; kt < 512; kt += 32) {
        #pragma unroll
        for (int r = 0; r < 2; ++r) {
            int s = tid + r * 256;
            int n_l = s / 8, kq = s % 8;
            int ng = n0 + n_l;
            const float* wrow = (ng < 512) ? (W_da + (size_t)ng * 512)
                                           : (W_fb + (size_t)(ng - 512) * 512);
            float4 w4 = *reinterpret_cast<const float4*>(wrow + kt + kq * 4);
            Ws[n_l][kq * 4 + 0] = w4.x; Ws[n_l][kq * 4 + 1] = w4.y;
            Ws[n_l][kq * 4 + 2] = w4.z; Ws[n_l][kq * 4 + 3] = w4.w;
        }
        __syncthreads();
        #pragma unroll
        for (int k = 0; k < 32; ++k) {
            const float* hrow = &heffT[(kt + k) * 33 + b4];
            float a0 = hrow[0], a1 = hrow[1], a2 = hrow[2], a3 = hrow[3];
            float w0 = Ws[nl][k], w1 = Ws[nl + 1][k];
            acc[0][0] += a0 * w0; acc[0][1] += a0 * w1;
            acc[1][0] += a1 * w0; acc[1][1] += a1 * w1;
            acc[2][0] += a2 * w0; acc[2][1] += a2 * w1;
            acc[3][0] += a3 * w0; acc[3][1] += a3 * w1;
        }
        __syncthreads();
    }
    #pragma unroll
    for (int j = 0; j < 2; ++j) {
        int ng = n0 + nl + j;
        float bias = (ng < 512) ? b_da[ng] : b_fb[ng - 512];
        #pragma unroll
        for (int i = 0; i < 4; ++i)
            attg[(size_t)(b4 + i) * 2560 + ng] = acc[i][j] + bias;
    }
}

// ---------------- k_e: e scores (grid 7 x 32) ----------------
__global__ __launch_bounds__(256) void k_e(
    const float* __restrict__ att1, const float* __restrict__ attg,
    const float* __restrict__ w_fa, const float* __restrict__ b_fa,
    float* __restrict__ e)
{
    __shared__ float att2s[ND];
    __shared__ float wfas[ND];
    int b = blockIdx.y, tid = threadIdx.x;
    const float* ag = attg + (size_t)b * 2560;
    for (int d = tid; d < ND; d += 256) { att2s[d] = ag[d]; wfas[d] = w_fa[d]; }
    __syncthreads();
    int w = tid >> 6, lane = tid & 63;
    int p0 = blockIdx.x * 28;
    const float* a1 = att1 + ((size_t)b * NP + p0) * ND;
    #pragma unroll
    for (int i = 0; i < 7; ++i) {
        int p = w + 4 * i;
        const float* row = a1 + (size_t)p * ND;
        float s = 0.f;
        #pragma unroll
        for (int j = 0; j < 2; ++j) {
            int d = j * 256 + lane * 4;
            float4 v = *reinterpret_cast<const float4*>(row + d);
            float4 a2 = *reinterpret_cast<const float4*>(&att2s[d]);
            float4 wf = *reinterpret_cast<const float4*>(&wfas[d]);
            s += fmaxf(v.x + a2.x, 0.f) * wf.x + fmaxf(v.y + a2.y, 0.f) * wf.y
               + fmaxf(v.z + a2.z, 0.f) * wf.z + fmaxf(v.w + a2.w, 0.f) * wf.w;
        }
        for (int off = 32; off > 0; off >>= 1) s += __shfl_down(s, off);
        if (lane == 0) e[(size_t)b * NP + p0 + p] = s + b_fa[0];
    }
}

// ---------------- k_awe: softmax + awe + gate + xh (grid 8 x 32) ----------------
__global__ __launch_bounds__(256) void k_awe(
    const float* __restrict__ enc, const int* __restrict__ sind, const int* __restrict__ dlens,
    const int* __restrict__ caps, const float* __restrict__ emb_W,
    const float* __restrict__ e, const float* __restrict__ attg,
    float* __restrict__ xh, float* __restrict__ out_alpha, int t)
{
    __shared__ float es[256];
    __shared__ float red[256];
    int kc = blockIdx.x, b = blockIdx.y, tid = threadIdx.x;
    float ev = -1e30f;
    if (tid < NP) { float v = e[(size_t)b * NP + tid]; es[tid] = v; ev = v; }
    red[tid] = ev; __syncthreads();
    for (int s2 = 128; s2 > 0; s2 >>= 1) { if (tid < s2) red[tid] = fmaxf(red[tid], red[tid + s2]); __syncthreads(); }
    float m = red[0]; __syncthreads();
    float xe = (tid < NP) ? expf(es[tid] - m) : 0.f;
    red[tid] = xe; __syncthreads();
    for (int s2 = 128; s2 > 0; s2 >>= 1) { if (tid < s2) red[tid] += red[tid + s2]; __syncthreads(); }
    float inv = 1.0f / red[0];
    __syncthreads();
    es[tid] = xe * inv;
    __syncthreads();

    int k = kc * 256 + tid;
    const float* ec = enc + (size_t)sind[b] * NP * NE + k;
    float s0 = 0.f, s1 = 0.f, s2v = 0.f, s3 = 0.f;
    #pragma unroll 4
    for (int p = 0; p < NP; p += 4) {
        s0 += es[p + 0] * ec[(size_t)(p + 0) * NE];
        s1 += es[p + 1] * ec[(size_t)(p + 1) * NE];
        s2v += es[p + 2] * ec[(size_t)(p + 2) * NE];
        s3 += es[p + 3] * ec[(size_t)(p + 3) * NE];
    }
    float awe = (s0 + s1) + (s2v + s3);
    float gp = attg[(size_t)b * 2560 + 512 + k];      // includes b_fb
    float gate = 1.f / (1.f + expf(-gp));
    xh[(size_t)b * 3072 + 512 + k] = gate * awe;
    if (kc == 0) {
        bool live = (t < dlens[b]);
        if (tid < NP) out_alpha[((size_t)b * NT + t) * NP + tid] = live ? es[tid] : 0.f;
        const float* er = emb_W + (size_t)caps[sind[b] * NL + t] * ND;
        xh[(size_t)b * 3072 + tid] = er[tid];
        xh[(size_t)b * 3072 + 256 + tid] = er[256 + tid];
    }
}

// ---------------- k_gates: gates GEMM partials (128 blocks: 32 ntiles x 4 ksplit of 768) ----------------
__global__ __launch_bounds__(256) void k_gates(
    const float* __restrict__ xh, const float* __restrict__ W_ih, const float* __restrict__ W_hh,
    float* __restrict__ gpart)
{
    __shared__ float smem[3200];
    int blk = blockIdx.x, tid = threadIdx.x;
    int nt = blk & 31, ks = blk >> 5;
    float* As = smem;
    float (*Ws)[33] = (float(*)[33])(smem + 1024);
    int n0 = nt * 64;
    int lb = tid / 8, lkq = tid % 8;
    int b4 = (tid / 32) * 4, nl = (tid % 32) * 2;
    float acc[4][2] = {};
    for (int kt = ks * 768; kt < ks * 768 + 768; kt += 32) {
        float4 a4 = *reinterpret_cast<const float4*>(xh + (size_t)lb * 3072 + kt + lkq * 4);
        As[(lkq * 4 + 0) * 32 + lb] = a4.x; As[(lkq * 4 + 1) * 32 + lb] = a4.y;
        As[(lkq * 4 + 2) * 32 + lb] = a4.z; As[(lkq * 4 + 3) * 32 + lb] = a4.w;
        #pragma unroll
        for (int r = 0; r < 2; ++r) {
            int s = tid + r * 256;
            int n_l = s / 8, kq = s % 8;
            int ng = n0 + n_l;
            int kk = kt + kq * 4;
            const float* wrow = (kk < 2560) ? (W_ih + (size_t)ng * 2560 + kk)
                                            : (W_hh + (size_t)ng * 512 + (kk - 2560));
            float4 w4 = *reinterpret_cast<const float4*>(wrow);
            Ws[n_l][kq * 4 + 0] = w4.x; Ws[n_l][kq * 4 + 1] = w4.y;
            Ws[n_l][kq * 4 + 2] = w4.z; Ws[n_l][kq * 4 + 3] = w4.w;
        }
        __syncthreads();
        #pragma unroll
        for (int k = 0; k < 32; ++k) {
            float4 av = *reinterpret_cast<const float4*>(&As[k * 32 + b4]);
            float w0 = Ws[nl][k], w1 = Ws[nl + 1][k];
            acc[0][0] += av.x * w0; acc[0][1] += av.x * w1;
            acc[1][0] += av.y * w0; acc[1][1] += av.y * w1;
            acc[2][0] += av.z * w0; acc[2][1] += av.z * w1;
            acc[3][0] += av.w * w0; acc[3][1] += av.w * w1;
        }
        __syncthreads();
    }
    float* Cp = gpart + (size_t)ks * NB * 2048;
    #pragma unroll
    for (int j = 0; j < 2; ++j)
        #pragma unroll
        for (int i = 0; i < 4; ++i)
            Cp[(size_t)(b4 + i) * 2048 + n0 + nl + j] = acc[i][j];
}

// ---------------- k_fin: final cell -> hseq[NT-1] ----------------
__global__ __launch_bounds__(256) void k_fin(
    const float* __restrict__ gpart, const float* __restrict__ hcbuf,
    const float* __restrict__ b_ih, const float* __restrict__ b_hh,
    float* __restrict__ hseq)
{
    int b = blockIdx.x;
    const float* hcR = hcbuf + (size_t)((NT - 1) & 1) * NB * 1024 + (size_t)b * 1024;
    for (int d = threadIdx.x; d < ND; d += 256) {
        float g0 = b_ih[d] + b_hh[d];
        float g1 = b_ih[512 + d] + b_hh[512 + d];
        float g2 = b_ih[1024 + d] + b_hh[1024 + d];
        float g3 = b_ih[1536 + d] + b_hh[1536 + d];
        #pragma unroll
        for (int ks = 0; ks < 4; ++ks) {
            const float* gp = gpart + ((size_t)ks * NB + b) * 2048;
            g0 += gp[d]; g1 += gp[512 + d]; g2 += gp[1024 + d]; g3 += gp[1536 + d];
        }
        float ig = 1.f / (1.f + expf(-g0));
        float fg = 1.f / (1.f + expf(-g1));
        float gt = tanhf(g2);
        float og = 1.f / (1.f + expf(-g3));
        float c_old = hcR[512 + d];
        float c_new = fg * c_old + ig * gt;
        float h_new = og * tanhf(c_new);
        hseq[((size_t)(NT - 1) * NB + b) * ND + d] = h_new;
    }
}

// ---------------- launcher ----------------
extern "C" void kernel_launch(void* const* d_in, const int* in_sizes, int n_in,
                              void* d_out, int out_size, void* d_ws, size_t ws_size,
                              hipStream_t stream)
{
    const float* enc   = (const float*)d_in[0];
    const int*   caps  = (const int*)d_in[1];
    const int*   clens = (const int*)d_in[2];
    const float* emb_W = (const float*)d_in[3];
    const float* W_ea  = (const float*)d_in[4];
    const float* b_ea  = (const float*)d_in[5];
    const float* W_da  = (const float*)d_in[6];
    const float* b_da  = (const float*)d_in[7];
    const float* w_fa  = (const float*)d_in[8];
    const float* b_fa  = (const float*)d_in[9];
    const float* W_ih  = (const float*)d_in[10];
    const float* b_ih  = (const float*)d_in[11];
    const float* W_hh  = (const float*)d_in[12];
    const float* b_hh  = (const float*)d_in[13];
    const float* W_h0  = (const float*)d_in[14];
    const float* b_h0  = (const float*)d_in[15];
    const float* W_c0  = (const float*)d_in[16];
    const float* b_c0  = (const float*)d_in[17];
    const float* W_fb  = (const float*)d_in[18];
    const float* b_fb  = (const float*)d_in[19];
    const float* W_fc  = (const float*)d_in[20];
    const float* b_fc  = (const float*)d_in[21];

    float* out = (float*)d_out;
    float* out_alpha = out + (size_t)NB * NT * NV;

    int* iws    = (int*)d_ws;
    int* sind   = iws;
    int* dlens  = iws + 32;
    int* rowmap = iws + 64;
    int* mpad   = iws + 704;
    float* base = (float*)d_ws + 1024;
    float* mean_enc = base;                         // 65536
    float* hcbuf = mean_enc + NB * NE;              // 2*32*1024 = 65536
    float* attg  = hcbuf + 2 * NB * 1024;           // 81920
    float* xh    = attg + NB * 2560;                // 98304
    float* e     = xh + NB * 3072;                  // 6272
    float* gpart = e + NB * NP;                     // 4*32*2048 = 262144
    float* hseq  = gpart + 4 * NB * 2048;           // 327680
    float* att1  = hseq + (size_t)NT * NB * ND;     // 3211264

    k_sort<<<1, 64, 0, stream>>>(clens, sind, dlens, rowmap, mpad);
    k_zero<<<NB * NT, 256, 0, stream>>>(dlens, out);
    k_mean<<<dim3(NE / 256, NB), 256, 0, stream>>>(enc, sind, mean_enc);
    gemm_skinny<<<dim3(16), 256, 0, stream>>>(mean_enc, W_h0, W_c0, b_h0, b_c0, hcbuf, xh);
    gemm_att1<<<dim3(832), 256, 0, stream>>>(enc, W_ea, b_ea, att1, sind);

    for (int t = 0; t < NT; ++t) {
        kA<<<dim3(40), 256, 0, stream>>>(gpart, dlens, W_da, W_fb, b_da, b_fb,
                                         b_ih, b_hh, hcbuf, attg, hseq, xh, t);
        k_e<<<dim3(7, NB), 256, 0, stream>>>(att1, attg, w_fa, b_fa, e);
        k_awe<<<dim3(8, NB), 256, 0, stream>>>(enc, sind, dlens, caps, emb_W,
                                               e, attg, xh, out_alpha, t);
        k_gates<<<dim3(128), 256, 0, stream>>>(xh, W_ih, W_hh, gpart);
    }
    k_fin<<<dim3(NB), 256, 0, stream>>>(gpart, hcbuf, b_ih, b_hh, hseq);

    gemm_preds<<<dim3(10, NV / 128), 256, 0, stream>>>(hseq, W_fc, b_fc, out, rowmap, mpad);
}

// Round 10
// 1882.307 us; speedup vs baseline: 1.7307x; 1.7307x over previous
//
#include <hip/hip_runtime.h>
#include <hip/hip_bf16.h>
#include <cstddef>

#define NB 32      // batch
#define NP 196     // pixels
#define NE 2048    // encoder dim
#define ND 512     // decoder/att/emb dim
#define NV 32000   // vocab
#define NL 21
#define NT 20      // decode steps

typedef __attribute__((ext_vector_type(8))) short short8;   // 8 bf16 (4 VGPRs) per guide §3
typedef __attribute__((ext_vector_type(4))) float f32x4;

__device__ __forceinline__ unsigned short f2b(float f) {
    __hip_bfloat16 h = __float2bfloat16(f);      // RNE
    return *reinterpret_cast<unsigned short*>(&h);
}
__device__ __forceinline__ float b2f_lo(unsigned int u) {
    union { unsigned int i; float f; } v; v.i = u << 16; return v.f;
}
__device__ __forceinline__ float b2f_hi(unsigned int u) {
    union { unsigned int i; float f; } v; v.i = u & 0xffff0000u; return v.f;
}

// ---------------- setup ----------------

__global__ void k_sort(const int* __restrict__ lens, int* __restrict__ sind, int* __restrict__ dlens,
                       int* __restrict__ rowmap, int* __restrict__ mpad)
{
    int i = threadIdx.x;
    if (i < NB) {
        int li = lens[i];
        int r = 0;
        for (int j = 0; j < NB; ++j) {
            int lj = lens[j];
            if (lj > li || (lj == li && j < i)) ++r;
        }
        sind[r] = i;
        dlens[r] = li - 1;
    }
    __syncthreads();
    if (i == 0) {
        int c = 0;
        for (int t = 0; t < NT; ++t)
            for (int b = 0; b < NB; ++b)
                if (t < dlens[b]) rowmap[c++] = t * NB + b;
        int pad = (c + 63) & ~63;
        for (int r = c; r < pad; ++r) rowmap[r] = -1;
        mpad[0] = pad;
    }
}

__global__ __launch_bounds__(256) void k_mean(const float* __restrict__ enc, const int* __restrict__ sind,
                                              float* __restrict__ mean_enc)
{
    int b = blockIdx.y;
    int k = blockIdx.x * 256 + threadIdx.x;
    const float* e = enc + (size_t)sind[b] * NP * NE + k;
    float s0 = 0.f, s1 = 0.f, s2 = 0.f, s3 = 0.f;
    for (int p = 0; p < NP; p += 4) {
        s0 += e[(size_t)(p + 0) * NE];
        s1 += e[(size_t)(p + 1) * NE];
        s2 += e[(size_t)(p + 2) * NE];
        s3 += e[(size_t)(p + 3) * NE];
    }
    mean_enc[(size_t)b * NE + k] = (s0 + s1 + s2 + s3) * (1.0f / NP);
}

__global__ __launch_bounds__(256) void k_zero(const int* __restrict__ dlens, float* __restrict__ out)
{
    int b = blockIdx.x / NT, t = blockIdx.x % NT;
    if (t < dlens[b]) return;
    float4 z = {0.f, 0.f, 0.f, 0.f};
    float4* row = (float4*)(out + ((size_t)b * NT + t) * NV);
    for (int i = threadIdx.x; i < NV / 4; i += 256) row[i] = z;
}

// ---------------- skinny GEMM: h0/c0 into hc; seeds xh h-part ----------------
__global__ __launch_bounds__(256) void gemm_skinny(
    const float* __restrict__ A0, const float* __restrict__ W0a, const float* __restrict__ W0b,
    const float* __restrict__ ba, const float* __restrict__ bb,
    float* __restrict__ C, float* __restrict__ xh)
{
    __shared__ float As[32][32];
    __shared__ float Ws[64][33];
    int n0 = blockIdx.x * 64;
    int tid = threadIdx.x;
    int lb = tid / 8, lkq = tid % 8;
    int b4 = (tid / 32) * 4, nl = (tid % 32) * 2;
    float acc[4][2] = {};
    for (int kt = 0; kt < NE; kt += 32) {
        float4 a4 = *reinterpret_cast<const float4*>(A0 + (size_t)lb * NE + kt + lkq * 4);
        As[lkq * 4 + 0][lb] = a4.x; As[lkq * 4 + 1][lb] = a4.y;
        As[lkq * 4 + 2][lb] = a4.z; As[lkq * 4 + 3][lb] = a4.w;
        #pragma unroll
        for (int r = 0; r < 2; ++r) {
            int s = tid + r * 256;
            int n_l = s / 8, kq = s % 8;
            int ng = n0 + n_l;
            const float* wrow = (ng < 512) ? (W0a + (size_t)ng * NE)
                                           : (W0b + (size_t)(ng - 512) * NE);
            float4 w4 = *reinterpret_cast<const float4*>(wrow + kt + kq * 4);
            Ws[n_l][kq * 4 + 0] = w4.x; Ws[n_l][kq * 4 + 1] = w4.y;
            Ws[n_l][kq * 4 + 2] = w4.z; Ws[n_l][kq * 4 + 3] = w4.w;
        }
        __syncthreads();
        #pragma unroll
        for (int k = 0; k < 32; ++k) {
            float4 av = *reinterpret_cast<const float4*>(&As[k][b4]);
            float w0 = Ws[nl][k], w1 = Ws[nl + 1][k];
            acc[0][0] += av.x * w0; acc[0][1] += av.x * w1;
            acc[1][0] += av.y * w0; acc[1][1] += av.y * w1;
            acc[2][0] += av.z * w0; acc[2][1] += av.z * w1;
            acc[3][0] += av.w * w0; acc[3][1] += av.w * w1;
        }
        __syncthreads();
    }
    #pragma unroll
    for (int j = 0; j < 2; ++j) {
        int ng = n0 + nl + j;
        float bias = (ng < 512) ? ba[ng] : bb[ng - 512];
        #pragma unroll
        for (int i = 0; i < 4; ++i) {
            float v = acc[i][j] + bias;
            int b = b4 + i;
            C[(size_t)b * 1024 + ng] = v;
            if (ng < 512) xh[(size_t)b * 3072 + 2560 + ng] = v;
        }
    }
}

// ---------------- att1 GEMM (bf16 MFMA): att1B[6272][512] = encS @ W_ea^T + b_ea ----------------
// BM=64 BN=64 BK=32, 4 waves (wave w: rows w*16..w*16+16, all 64 cols).
// XCD swizzle: fid=(c + 8x + 64pg), p = pg*8+c -> same-p blocks share XCD (proven FETCH 204->49MB).
__global__ __launch_bounds__(256) void gemm_att1_mfma(
    const float* __restrict__ enc, const float* __restrict__ W_ea,
    const float* __restrict__ bias, unsigned short* __restrict__ att1B,
    const int* __restrict__ sind)
{
    int fid = blockIdx.x;
    int c = fid & 7, x = (fid >> 3) & 7, pg = fid >> 6;
    int p = pg * 8 + c;
    if (p >= 98) return;
    int bm0 = p * 64, bn0 = x * 64;
    __shared__ unsigned short As[64][40];   // 32 data + 8 pad (80B rows, 16B aligned)
    __shared__ unsigned short Bs[64][40];
    int tid = threadIdx.x;
    int w = tid >> 6, lane = tid & 63;
    int srow = tid >> 2, schunk = (tid & 3) * 8;
    int mg = bm0 + srow;
    int bidx = mg / NP, pp = mg - bidx * NP;
    const float* arow = enc + ((size_t)sind[bidx] * NP + pp) * NE + schunk;
    const float* brow = W_ea + (size_t)(bn0 + srow) * NE + schunk;
    int frow = lane & 15, fk = (lane >> 4) * 8;
    f32x4 acc[4] = {};
    for (int kt = 0; kt < NE; kt += 32) {
        float4 a0 = *reinterpret_cast<const float4*>(arow + kt);
        float4 a1 = *reinterpret_cast<const float4*>(arow + kt + 4);
        float4 b0 = *reinterpret_cast<const float4*>(brow + kt);
        float4 b1 = *reinterpret_cast<const float4*>(brow + kt + 4);
        uint4 av, bv;
        av.x = f2b(a0.x) | ((unsigned)f2b(a0.y) << 16);
        av.y = f2b(a0.z) | ((unsigned)f2b(a0.w) << 16);
        av.z = f2b(a1.x) | ((unsigned)f2b(a1.y) << 16);
        av.w = f2b(a1.z) | ((unsigned)f2b(a1.w) << 16);
        bv.x = f2b(b0.x) | ((unsigned)f2b(b0.y) << 16);
        bv.y = f2b(b0.z) | ((unsigned)f2b(b0.w) << 16);
        bv.z = f2b(b1.x) | ((unsigned)f2b(b1.y) << 16);
        bv.w = f2b(b1.z) | ((unsigned)f2b(b1.w) << 16);
        *reinterpret_cast<uint4*>(&As[srow][schunk]) = av;
        *reinterpret_cast<uint4*>(&Bs[srow][schunk]) = bv;
        __syncthreads();
        short8 af = *reinterpret_cast<const short8*>(&As[w * 16 + frow][fk]);
        #pragma unroll
        for (int n = 0; n < 4; ++n) {
            short8 bf = *reinterpret_cast<const short8*>(&Bs[n * 16 + frow][fk]);
            acc[n] = __builtin_amdgcn_mfma_f32_16x16x32_bf16(af, bf, acc[n], 0, 0, 0);
        }
        __syncthreads();
    }
    int crow = bm0 + w * 16 + (lane >> 4) * 4;
    int ccol0 = lane & 15;
    #pragma unroll
    for (int n = 0; n < 4; ++n) {
        int col = bn0 + n * 16 + ccol0;
        float bb2 = bias[col];
        #pragma unroll
        for (int i = 0; i < 4; ++i)
            att1B[(size_t)(crow + i) * ND + col] = f2b(acc[n][i] + bb2);
    }
}

// ---------------- preds GEMM (bf16 MFMA): out = hseqB @ W_fc^T + b_fc, live rows ----------------
// BM=64 BN=128 BK=32, 4 waves; wave w: rows w*16..16, 8 col-frags.
__global__ __launch_bounds__(256) void gemm_preds_mfma(
    const unsigned short* __restrict__ hseqB, const float* __restrict__ W_fc,
    const float* __restrict__ bias, float* __restrict__ out,
    const int* __restrict__ rowmap, const int* __restrict__ mpad)
{
    int bm0 = blockIdx.x * 64;
    if (bm0 >= mpad[0]) return;
    int bn0 = blockIdx.y * 128;
    __shared__ unsigned short As[64][40];
    __shared__ unsigned short Bs[128][40];
    int tid = threadIdx.x;
    int w = tid >> 6, lane = tid & 63;
    int srow = tid >> 2, schunk = (tid & 3) * 8;
    int rid = rowmap[bm0 + srow];
    const unsigned short* aptr = hseqB + (size_t)(rid < 0 ? 0 : rid) * ND + schunk;
    const float* bptr0 = W_fc + (size_t)(bn0 + srow) * ND + schunk;
    const float* bptr1 = W_fc + (size_t)(bn0 + 64 + srow) * ND + schunk;
    int frow = lane & 15, fk = (lane >> 4) * 8;
    f32x4 acc[8] = {};
    for (int kt = 0; kt < ND; kt += 32) {
        uint4 av = *reinterpret_cast<const uint4*>(aptr + kt);
        float4 c0 = *reinterpret_cast<const float4*>(bptr0 + kt);
        float4 c1 = *reinterpret_cast<const float4*>(bptr0 + kt + 4);
        float4 d0 = *reinterpret_cast<const float4*>(bptr1 + kt);
        float4 d1 = *reinterpret_cast<const float4*>(bptr1 + kt + 4);
        uint4 bv0, bv1;
        bv0.x = f2b(c0.x) | ((unsigned)f2b(c0.y) << 16);
        bv0.y = f2b(c0.z) | ((unsigned)f2b(c0.w) << 16);
        bv0.z = f2b(c1.x) | ((unsigned)f2b(c1.y) << 16);
        bv0.w = f2b(c1.z) | ((unsigned)f2b(c1.w) << 16);
        bv1.x = f2b(d0.x) | ((unsigned)f2b(d0.y) << 16);
        bv1.y = f2b(d0.z) | ((unsigned)f2b(d0.w) << 16);
        bv1.z = f2b(d1.x) | ((unsigned)f2b(d1.y) << 16);
        bv1.w = f2b(d1.z) | ((unsigned)f2b(d1.w) << 16);
        *reinterpret_cast<uint4*>(&As[srow][schunk]) = av;
        *reinterpret_cast<uint4*>(&Bs[srow][schunk]) = bv0;
        *reinterpret_cast<uint4*>(&Bs[64 + srow][schunk]) = bv1;
        __syncthreads();
        short8 af = *reinterpret_cast<const short8*>(&As[w * 16 + frow][fk]);
        #pragma unroll
        for (int n = 0; n < 8; ++n) {
            short8 bf = *reinterpret_cast<const short8*>(&Bs[n * 16 + frow][fk]);
            acc[n] = __builtin_amdgcn_mfma_f32_16x16x32_bf16(af, bf, acc[n], 0, 0, 0);
        }
        __syncthreads();
    }
    int rl0 = w * 16 + (lane >> 4) * 4;
    int ccol0 = lane & 15;
    #pragma unroll
    for (int i = 0; i < 4; ++i) {
        int rm = rowmap[bm0 + rl0 + i];
        if (rm < 0) continue;
        int t = rm / NB, b = rm % NB;
        float* orow = out + ((size_t)b * NT + t) * NV;
        #pragma unroll
        for (int n = 0; n < 8; ++n) {
            int col = bn0 + n * 16 + ccol0;
            orow[col] = acc[n][i] + bias[col];
        }
    }
}

// ---------------- k_attg: attg[32][2560] = h @ [W_da;W_fb]^T + [b_da;b_fb] (40 blocks) ----------------
__global__ __launch_bounds__(256) void k_attg(
    const float* __restrict__ hc, const float* __restrict__ W_da, const float* __restrict__ W_fb,
    const float* __restrict__ b_da, const float* __restrict__ b_fb, float* __restrict__ attg)
{
    __shared__ float As[32][32];
    __shared__ float Ws[64][33];
    int n0 = blockIdx.x * 64;
    int tid = threadIdx.x;
    int lb = tid / 8, lkq = tid % 8;
    int b4 = (tid / 32) * 4, nl = (tid % 32) * 2;
    float acc[4][2] = {};
    for (int kt = 0; kt < 512; kt += 32) {
        float4 a4 = *reinterpret_cast<const float4*>(hc + (size_t)lb * 1024 + kt + lkq * 4);
        As[lkq * 4 + 0][lb] = a4.x; As[lkq * 4 + 1][lb] = a4.y;
        As[lkq * 4 + 2][lb] = a4.z; As[lkq * 4 + 3][lb] = a4.w;
        #pragma unroll
        for (int r = 0; r < 2; ++r) {
            int s = tid + r * 256;
            int n_l = s / 8, kq = s % 8;
            int ng = n0 + n_l;
            const float* wrow = (ng < 512) ? (W_da + (size_t)ng * 512)
                                           : (W_fb + (size_t)(ng - 512) * 512);
            float4 w4 = *reinterpret_cast<const float4*>(wrow + kt + kq * 4);
            Ws[n_l][kq * 4 + 0] = w4.x; Ws[n_l][kq * 4 + 1] = w4.y;
            Ws[n_l][kq * 4 + 2] = w4.z; Ws[n_l][kq * 4 + 3] = w4.w;
        }
        __syncthreads();
        #pragma unroll
        for (int k = 0; k < 32; ++k) {
            float4 av = *reinterpret_cast<const float4*>(&As[k][b4]);
            float w0 = Ws[nl][k], w1 = Ws[nl + 1][k];
            acc[0][0] += av.x * w0; acc[0][1] += av.x * w1;
            acc[1][0] += av.y * w0; acc[1][1] += av.y * w1;
            acc[2][0] += av.z * w0; acc[2][1] += av.z * w1;
            acc[3][0] += av.w * w0; acc[3][1] += av.w * w1;
        }
        __syncthreads();
    }
    #pragma unroll
    for (int j = 0; j < 2; ++j) {
        int ng = n0 + nl + j;
        float bias = (ng < 512) ? b_da[ng] : b_fb[ng - 512];
        #pragma unroll
        for (int i = 0; i < 4; ++i)
            attg[(size_t)(b4 + i) * 2560 + ng] = acc[i][j] + bias;
    }
}

// ---------------- k_e: e scores from bf16 att1 (grid 7 x 32) ----------------
__global__ __launch_bounds__(256) void k_e(
    const unsigned short* __restrict__ att1B, const float* __restrict__ attg,
    const float* __restrict__ w_fa, const float* __restrict__ b_fa,
    float* __restrict__ e)
{
    __shared__ float att2s[ND];
    __shared__ float wfas[ND];
    int b = blockIdx.y, tid = threadIdx.x;
    const float* ag = attg + (size_t)b * 2560;
    for (int d = tid; d < ND; d += 256) { att2s[d] = ag[d]; wfas[d] = w_fa[d]; }
    __syncthreads();
    int w = tid >> 6, lane = tid & 63;
    int p0 = blockIdx.x * 28;
    const unsigned short* a1 = att1B + ((size_t)b * NP + p0) * ND;
    #pragma unroll
    for (int i = 0; i < 7; ++i) {
        int p = w + 4 * i;
        const unsigned short* row = a1 + (size_t)p * ND;
        float s = 0.f;
        #pragma unroll
        for (int j = 0; j < 2; ++j) {
            int d = j * 256 + lane * 4;
            uint2 u = *reinterpret_cast<const uint2*>(row + d);   // 4 bf16
            float v0 = b2f_lo(u.x), v1 = b2f_hi(u.x);
            float v2 = b2f_lo(u.y), v3 = b2f_hi(u.y);
            float4 a2 = *reinterpret_cast<const float4*>(&att2s[d]);
            float4 wf = *reinterpret_cast<const float4*>(&wfas[d]);
            s += fmaxf(v0 + a2.x, 0.f) * wf.x + fmaxf(v1 + a2.y, 0.f) * wf.y
               + fmaxf(v2 + a2.z, 0.f) * wf.z + fmaxf(v3 + a2.w, 0.f) * wf.w;
        }
        for (int off = 32; off > 0; off >>= 1) s += __shfl_down(s, off);
        if (lane == 0) e[(size_t)b * NP + p0 + p] = s + b_fa[0];
    }
}

// ---------------- k_awe: softmax + awe + gate + xh (grid 8 x 32) ----------------
__global__ __launch_bounds__(256) void k_awe(
    const float* __restrict__ enc, const int* __restrict__ sind, const int* __restrict__ dlens,
    const int* __restrict__ caps, const float* __restrict__ emb_W,
    const float* __restrict__ e, const float* __restrict__ attg,
    float* __restrict__ xh, float* __restrict__ out_alpha, int t)
{
    __shared__ float es[256];
    __shared__ float red[256];
    int kc = blockIdx.x, b = blockIdx.y, tid = threadIdx.x;
    float ev = -1e30f;
    if (tid < NP) { float v = e[(size_t)b * NP + tid]; es[tid] = v; ev = v; }
    red[tid] = ev; __syncthreads();
    for (int s2 = 128; s2 > 0; s2 >>= 1) { if (tid < s2) red[tid] = fmaxf(red[tid], red[tid + s2]); __syncthreads(); }
    float m = red[0]; __syncthreads();
    float xe = (tid < NP) ? expf(es[tid] - m) : 0.f;
    red[tid] = xe; __syncthreads();
    for (int s2 = 128; s2 > 0; s2 >>= 1) { if (tid < s2) red[tid] += red[tid + s2]; __syncthreads(); }
    float inv = 1.0f / red[0];
    __syncthreads();
    es[tid] = xe * inv;
    __syncthreads();

    int k = kc * 256 + tid;
    const float* ec = enc + (size_t)sind[b] * NP * NE + k;
    float s0 = 0.f, s1 = 0.f, s2v = 0.f, s3 = 0.f;
    #pragma unroll 4
    for (int p = 0; p < NP; p += 4) {
        s0 += es[p + 0] * ec[(size_t)(p + 0) * NE];
        s1 += es[p + 1] * ec[(size_t)(p + 1) * NE];
        s2v += es[p + 2] * ec[(size_t)(p + 2) * NE];
        s3 += es[p + 3] * ec[(size_t)(p + 3) * NE];
    }
    float awe = (s0 + s1) + (s2v + s3);
    float gp = attg[(size_t)b * 2560 + 512 + k];      // includes b_fb
    float gate = 1.f / (1.f + expf(-gp));
    xh[(size_t)b * 3072 + 512 + k] = gate * awe;
    if (kc == 0) {
        bool live = (t < dlens[b]);
        if (tid < NP) out_alpha[((size_t)b * NT + t) * NP + tid] = live ? es[tid] : 0.f;
        const float* er = emb_W + (size_t)caps[sind[b] * NL + t] * ND;
        xh[(size_t)b * 3072 + tid] = er[tid];
        xh[(size_t)b * 3072 + 256 + tid] = er[256 + tid];
    }
}

// ---------------- k_gates: gates GEMM partials (128 blocks: 32 ntiles x 4 ksplit of 768) ----------------
__global__ __launch_bounds__(256) void k_gates(
    const float* __restrict__ xh, const float* __restrict__ W_ih, const float* __restrict__ W_hh,
    float* __restrict__ gpart)
{
    __shared__ float smem[3200];
    int blk = blockIdx.x, tid = threadIdx.x;
    int nt = blk & 31, ks = blk >> 5;
    float* As = smem;
    float (*Ws)[33] = (float(*)[33])(smem + 1024);
    int n0 = nt * 64;
    int lb = tid / 8, lkq = tid % 8;
    int b4 = (tid / 32) * 4, nl = (tid % 32) * 2;
    float acc[4][2] = {};
    for (int kt = ks * 768; kt < ks * 768 + 768; kt += 32) {
        float4 a4 = *reinterpret_cast<const float4*>(xh + (size_t)lb * 3072 + kt + lkq * 4);
        As[(lkq * 4 + 0) * 32 + lb] = a4.x; As[(lkq * 4 + 1) * 32 + lb] = a4.y;
        As[(lkq * 4 + 2) * 32 + lb] = a4.z; As[(lkq * 4 + 3) * 32 + lb] = a4.w;
        #pragma unroll
        for (int r = 0; r < 2; ++r) {
            int s = tid + r * 256;
            int n_l = s / 8, kq = s % 8;
            int ng = n0 + n_l;
            int kk = kt + kq * 4;
            const float* wrow = (kk < 2560) ? (W_ih + (size_t)ng * 2560 + kk)
                                            : (W_hh + (size_t)ng * 512 + (kk - 2560));
            float4 w4 = *reinterpret_cast<const float4*>(wrow);
            Ws[n_l][kq * 4 + 0] = w4.x; Ws[n_l][kq * 4 + 1] = w4.y;
            Ws[n_l][kq * 4 + 2] = w4.z; Ws[n_l][kq * 4 + 3] = w4.w;
        }
        __syncthreads();
        #pragma unroll
        for (int k = 0; k < 32; ++k) {
            float4 av = *reinterpret_cast<const float4*>(&As[k * 32 + b4]);
            float w0 = Ws[nl][k], w1 = Ws[nl + 1][k];
            acc[0][0] += av.x * w0; acc[0][1] += av.x * w1;
            acc[1][0] += av.y * w0; acc[1][1] += av.y * w1;
            acc[2][0] += av.z * w0; acc[2][1] += av.z * w1;
            acc[3][0] += av.w * w0; acc[3][1] += av.w * w1;
        }
        __syncthreads();
    }
    float* Cp = gpart + (size_t)ks * NB * 2048;
    #pragma unroll
    for (int j = 0; j < 2; ++j)
        #pragma unroll
        for (int i = 0; i < 4; ++i)
            Cp[(size_t)(b4 + i) * 2048 + n0 + nl + j] = acc[i][j];
}

// ---------------- k_cell: reduce partials + LSTM cell; hseq stored bf16 ----------------
__global__ __launch_bounds__(256) void k_cell(
    const float* __restrict__ gpart, const int* __restrict__ dlens,
    const float* __restrict__ b_ih, const float* __restrict__ b_hh,
    float* __restrict__ hc, unsigned short* __restrict__ hseqB, float* __restrict__ xh, int t)
{
    int b = blockIdx.x;
    for (int d = threadIdx.x; d < ND; d += 256) {
        float g0 = b_ih[d] + b_hh[d];
        float g1 = b_ih[512 + d] + b_hh[512 + d];
        float g2 = b_ih[1024 + d] + b_hh[1024 + d];
        float g3 = b_ih[1536 + d] + b_hh[1536 + d];
        #pragma unroll
        for (int ks = 0; ks < 4; ++ks) {
            const float* gp = gpart + ((size_t)ks * NB + b) * 2048;
            g0 += gp[d]; g1 += gp[512 + d]; g2 += gp[1024 + d]; g3 += gp[1536 + d];
        }
        float ig = 1.f / (1.f + expf(-g0));
        float fg = 1.f / (1.f + expf(-g1));
        float gt = tanhf(g2);
        float og = 1.f / (1.f + expf(-g3));
        float c_old = hc[(size_t)b * 1024 + 512 + d];
        float c_new = fg * c_old + ig * gt;
        float h_new = og * tanhf(c_new);
        hseqB[((size_t)t * NB + b) * ND + d] = f2b(h_new);
        if (t < dlens[b]) {
            hc[(size_t)b * 1024 + d] = h_new;
            hc[(size_t)b * 1024 + 512 + d] = c_new;
            xh[(size_t)b * 3072 + 2560 + d] = h_new;
        }
    }
}

// ---------------- launcher ----------------
extern "C" void kernel_launch(void* const* d_in, const int* in_sizes, int n_in,
                              void* d_out, int out_size, void* d_ws, size_t ws_size,
                              hipStream_t stream)
{
    const float* enc   = (const float*)d_in[0];
    const int*   caps  = (const int*)d_in[1];
    const int*   clens = (const int*)d_in[2];
    const float* emb_W = (const float*)d_in[3];
    const float* W_ea  = (const float*)d_in[4];
    const float* b_ea  = (const float*)d_in[5];
    const float* W_da  = (const float*)d_in[6];
    const float* b_da  = (const float*)d_in[7];
    const float* w_fa  = (const float*)d_in[8];
    const float* b_fa  = (const float*)d_in[9];
    const float* W_ih  = (const float*)d_in[10];
    const float* b_ih  = (const float*)d_in[11];
    const float* W_hh  = (const float*)d_in[12];
    const float* b_hh  = (const float*)d_in[13];
    const float* W_h0  = (const float*)d_in[14];
    const float* b_h0  = (const float*)d_in[15];
    const float* W_c0  = (const float*)d_in[16];
    const float* b_c0  = (const float*)d_in[17];
    const float* W_fb  = (const float*)d_in[18];
    const float* b_fb  = (const float*)d_in[19];
    const float* W_fc  = (const float*)d_in[20];
    const float* b_fc  = (const float*)d_in[21];

    float* out = (float*)d_out;
    float* out_alpha = out + (size_t)NB * NT * NV;

    int* iws    = (int*)d_ws;
    int* sind   = iws;
    int* dlens  = iws + 32;
    int* rowmap = iws + 64;
    int* mpad   = iws + 704;
    float* base = (float*)d_ws + 1024;
    float* mean_enc = base;                         // 65536
    float* hc    = mean_enc + NB * NE;              // 32768
    float* attg  = hc + NB * 1024;                  // 81920
    float* xh    = attg + NB * 2560;                // 98304
    float* e     = xh + NB * 3072;                  // 6272
    float* gpart = e + NB * NP;                     // 262144
    unsigned short* att1B = (unsigned short*)(gpart + 4 * NB * 2048);   // 6272*512 bf16
    unsigned short* hseqB = att1B + (size_t)NB * NP * ND;               // 640*512 bf16

    k_sort<<<1, 64, 0, stream>>>(clens, sind, dlens, rowmap, mpad);
    k_zero<<<NB * NT, 256, 0, stream>>>(dlens, out);
    k_mean<<<dim3(NE / 256, NB), 256, 0, stream>>>(enc, sind, mean_enc);
    gemm_skinny<<<dim3(16), 256, 0, stream>>>(mean_enc, W_h0, W_c0, b_h0, b_c0, hc, xh);
    gemm_att1_mfma<<<dim3(832), 256, 0, stream>>>(enc, W_ea, b_ea, att1B, sind);

    for (int t = 0; t < NT; ++t) {
        k_attg<<<dim3(40), 256, 0, stream>>>(hc, W_da, W_fb, b_da, b_fb, attg);
        k_e<<<dim3(7, NB), 256, 0, stream>>>(att1B, attg, w_fa, b_fa, e);
        k_awe<<<dim3(8, NB), 256, 0, stream>>>(enc, sind, dlens, caps, emb_W,
                                               e, attg, xh, out_alpha, t);
        k_gates<<<dim3(128), 256, 0, stream>>>(xh, W_ih, W_hh, gpart);
        k_cell<<<dim3(NB), 256, 0, stream>>>(gpart, dlens, b_ih, b_hh, hc, hseqB, xh, t);
    }

    gemm_preds_mfma<<<dim3(10, NV / 128), 256, 0, stream>>>(hseqB, W_fc, b_fc, out, rowmap, mpad);
}

// Round 11
// 1777.821 us; speedup vs baseline: 1.8324x; 1.0588x over previous
//
#include <hip/hip_runtime.h>
#include <hip/hip_bf16.h>
#include <cstddef>

#define NB 32      // batch
#define NP 196     // pixels
#define NE 2048    // encoder dim
#define ND 512     // decoder/att/emb dim
#define NV 32000   // vocab
#define NL 21
#define NT 20      // decode steps

typedef __attribute__((ext_vector_type(8))) short short8;   // 8 bf16 (4 VGPRs)
typedef __attribute__((ext_vector_type(4))) float f32x4;

__device__ __forceinline__ unsigned short f2b(float f) {
    __hip_bfloat16 h = __float2bfloat16(f);      // RNE
    return *reinterpret_cast<unsigned short*>(&h);
}
__device__ __forceinline__ float b2f_lo(unsigned int u) {
    union { unsigned int i; float f; } v; v.i = u << 16; return v.f;
}
__device__ __forceinline__ float b2f_hi(unsigned int u) {
    union { unsigned int i; float f; } v; v.i = u & 0xffff0000u; return v.f;
}

// ---------------- setup ----------------

__global__ void k_sort(const int* __restrict__ lens, int* __restrict__ sind, int* __restrict__ dlens,
                       int* __restrict__ rowmap, int* __restrict__ mpad)
{
    int i = threadIdx.x;
    if (i < NB) {
        int li = lens[i];
        int r = 0;
        for (int j = 0; j < NB; ++j) {
            int lj = lens[j];
            if (lj > li || (lj == li && j < i)) ++r;
        }
        sind[r] = i;
        dlens[r] = li - 1;
    }
    __syncthreads();
    if (i == 0) {
        int c = 0;
        for (int t = 0; t < NT; ++t)
            for (int b = 0; b < NB; ++b)
                if (t < dlens[b]) rowmap[c++] = t * NB + b;
        int pad = (c + 63) & ~63;
        for (int r = c; r < pad; ++r) rowmap[r] = -1;
        mpad[0] = pad;
    }
}

__global__ __launch_bounds__(256) void k_mean(const float* __restrict__ enc, const int* __restrict__ sind,
                                              float* __restrict__ mean_enc)
{
    int b = blockIdx.y;
    int k = blockIdx.x * 256 + threadIdx.x;
    const float* e = enc + (size_t)sind[b] * NP * NE + k;
    float s0 = 0.f, s1 = 0.f, s2 = 0.f, s3 = 0.f;
    for (int p = 0; p < NP; p += 4) {
        s0 += e[(size_t)(p + 0) * NE];
        s1 += e[(size_t)(p + 1) * NE];
        s2 += e[(size_t)(p + 2) * NE];
        s3 += e[(size_t)(p + 3) * NE];
    }
    mean_enc[(size_t)b * NE + k] = (s0 + s1 + s2 + s3) * (1.0f / NP);
}

__global__ __launch_bounds__(256) void k_zero(const int* __restrict__ dlens, float* __restrict__ out)
{
    int b = blockIdx.x / NT, t = blockIdx.x % NT;
    if (t < dlens[b]) return;
    float4 z = {0.f, 0.f, 0.f, 0.f};
    float4* row = (float4*)(out + ((size_t)b * NT + t) * NV);
    for (int i = threadIdx.x; i < NV / 4; i += 256) row[i] = z;
}

// ---------------- h0/c0 skinny GEMM, split-K=8 (grid 16 x 8) -> partials in spart ----------------
__global__ __launch_bounds__(256) void gemm_skinny_split(
    const float* __restrict__ A0, const float* __restrict__ W0a, const float* __restrict__ W0b,
    float* __restrict__ spart)
{
    __shared__ float As[32][32];
    __shared__ float Ws[64][33];
    int n0 = blockIdx.x * 64;
    int ks = blockIdx.y;
    int tid = threadIdx.x;
    int lb = tid / 8, lkq = tid % 8;
    int b4 = (tid / 32) * 4, nl = (tid % 32) * 2;
    float acc[4][2] = {};
    for (int kt = ks * 256; kt < ks * 256 + 256; kt += 32) {
        float4 a4 = *reinterpret_cast<const float4*>(A0 + (size_t)lb * NE + kt + lkq * 4);
        As[lkq * 4 + 0][lb] = a4.x; As[lkq * 4 + 1][lb] = a4.y;
        As[lkq * 4 + 2][lb] = a4.z; As[lkq * 4 + 3][lb] = a4.w;
        #pragma unroll
        for (int r = 0; r < 2; ++r) {
            int s = tid + r * 256;
            int n_l = s / 8, kq = s % 8;
            int ng = n0 + n_l;
            const float* wrow = (ng < 512) ? (W0a + (size_t)ng * NE)
                                           : (W0b + (size_t)(ng - 512) * NE);
            float4 w4 = *reinterpret_cast<const float4*>(wrow + kt + kq * 4);
            Ws[n_l][kq * 4 + 0] = w4.x; Ws[n_l][kq * 4 + 1] = w4.y;
            Ws[n_l][kq * 4 + 2] = w4.z; Ws[n_l][kq * 4 + 3] = w4.w;
        }
        __syncthreads();
        #pragma unroll
        for (int k = 0; k < 32; ++k) {
            float4 av = *reinterpret_cast<const float4*>(&As[k][b4]);
            float w0 = Ws[nl][k], w1 = Ws[nl + 1][k];
            acc[0][0] += av.x * w0; acc[0][1] += av.x * w1;
            acc[1][0] += av.y * w0; acc[1][1] += av.y * w1;
            acc[2][0] += av.z * w0; acc[2][1] += av.z * w1;
            acc[3][0] += av.w * w0; acc[3][1] += av.w * w1;
        }
        __syncthreads();
    }
    float* Cp = spart + (size_t)ks * NB * 1024;
    #pragma unroll
    for (int j = 0; j < 2; ++j)
        #pragma unroll
        for (int i = 0; i < 4; ++i)
            Cp[(size_t)(b4 + i) * 1024 + n0 + nl + j] = acc[i][j];
}

// combine partials + bias -> hc; seed xh h-part (grid NB)
__global__ __launch_bounds__(256) void k_hc0(
    const float* __restrict__ spart, const float* __restrict__ ba, const float* __restrict__ bb,
    float* __restrict__ hc, float* __restrict__ xh)
{
    int b = blockIdx.x;
    for (int ng = threadIdx.x; ng < 1024; ng += 256) {
        float s = (ng < 512) ? ba[ng] : bb[ng - 512];
        #pragma unroll
        for (int ks = 0; ks < 8; ++ks)
            s += spart[(size_t)ks * NB * 1024 + (size_t)b * 1024 + ng];
        hc[(size_t)b * 1024 + ng] = s;
        if (ng < 512) xh[(size_t)b * 3072 + 2560 + ng] = s;
    }
}

// ---------------- att1 GEMM (bf16 MFMA): att1B[6272][512] = encS @ W_ea^T + b_ea ----------------
// BM=64 BN=64 BK=32, 4 waves. XCD swizzle: fid=(c + 8x + 64pg), p = pg*8+c.
__global__ __launch_bounds__(256) void gemm_att1_mfma(
    const float* __restrict__ enc, const float* __restrict__ W_ea,
    const float* __restrict__ bias, unsigned short* __restrict__ att1B,
    const int* __restrict__ sind)
{
    int fid = blockIdx.x;
    int c = fid & 7, x = (fid >> 3) & 7, pg = fid >> 6;
    int p = pg * 8 + c;
    if (p >= 98) return;
    int bm0 = p * 64, bn0 = x * 64;
    __shared__ unsigned short As[64][40];   // 32 data + 8 pad
    __shared__ unsigned short Bs[64][40];
    int tid = threadIdx.x;
    int w = tid >> 6, lane = tid & 63;
    int srow = tid >> 2, schunk = (tid & 3) * 8;
    int mg = bm0 + srow;
    int bidx = mg / NP, pp = mg - bidx * NP;
    const float* arow = enc + ((size_t)sind[bidx] * NP + pp) * NE + schunk;
    const float* brow = W_ea + (size_t)(bn0 + srow) * NE + schunk;
    int frow = lane & 15, fk = (lane >> 4) * 8;
    f32x4 acc[4] = {};
    for (int kt = 0; kt < NE; kt += 32) {
        float4 a0 = *reinterpret_cast<const float4*>(arow + kt);
        float4 a1 = *reinterpret_cast<const float4*>(arow + kt + 4);
        float4 b0 = *reinterpret_cast<const float4*>(brow + kt);
        float4 b1 = *reinterpret_cast<const float4*>(brow + kt + 4);
        uint4 av, bv;
        av.x = f2b(a0.x) | ((unsigned)f2b(a0.y) << 16);
        av.y = f2b(a0.z) | ((unsigned)f2b(a0.w) << 16);
        av.z = f2b(a1.x) | ((unsigned)f2b(a1.y) << 16);
        av.w = f2b(a1.z) | ((unsigned)f2b(a1.w) << 16);
        bv.x = f2b(b0.x) | ((unsigned)f2b(b0.y) << 16);
        bv.y = f2b(b0.z) | ((unsigned)f2b(b0.w) << 16);
        bv.z = f2b(b1.x) | ((unsigned)f2b(b1.y) << 16);
        bv.w = f2b(b1.z) | ((unsigned)f2b(b1.w) << 16);
        *reinterpret_cast<uint4*>(&As[srow][schunk]) = av;
        *reinterpret_cast<uint4*>(&Bs[srow][schunk]) = bv;
        __syncthreads();
        short8 af = *reinterpret_cast<const short8*>(&As[w * 16 + frow][fk]);
        #pragma unroll
        for (int n = 0; n < 4; ++n) {
            short8 bf = *reinterpret_cast<const short8*>(&Bs[n * 16 + frow][fk]);
            acc[n] = __builtin_amdgcn_mfma_f32_16x16x32_bf16(af, bf, acc[n], 0, 0, 0);
        }
        __syncthreads();
    }
    int crow = bm0 + w * 16 + (lane >> 4) * 4;
    int ccol0 = lane & 15;
    #pragma unroll
    for (int n = 0; n < 4; ++n) {
        int col = bn0 + n * 16 + ccol0;
        float bb2 = bias[col];
        #pragma unroll
        for (int i = 0; i < 4; ++i)
            att1B[(size_t)(crow + i) * ND + col] = f2b(acc[n][i] + bb2);
    }
}

// ---------------- preds GEMM (bf16 MFMA), XCD-swizzled: all m-blocks of an n-panel share XCD ----
// fid = g*80 + m*8 + c ; n = g*8+c (W-panel), m = m-tile. fid%8 == c for all m of same n.
__global__ __launch_bounds__(256) void gemm_preds_mfma(
    const unsigned short* __restrict__ hseqB, const float* __restrict__ W_fc,
    const float* __restrict__ bias, float* __restrict__ out,
    const int* __restrict__ rowmap, const int* __restrict__ mpad)
{
    int fid = blockIdx.x;
    int c = fid & 7;
    int rem = fid >> 3;
    int m = rem % 10, g = rem / 10;
    int n = g * 8 + c;
    if (n >= 250) return;
    int bm0 = m * 64;
    if (bm0 >= mpad[0]) return;
    int bn0 = n * 128;
    __shared__ unsigned short As[64][40];
    __shared__ unsigned short Bs[128][40];
    int tid = threadIdx.x;
    int w = tid >> 6, lane = tid & 63;
    int srow = tid >> 2, schunk = (tid & 3) * 8;
    int rid = rowmap[bm0 + srow];
    const unsigned short* aptr = hseqB + (size_t)(rid < 0 ? 0 : rid) * ND + schunk;
    const float* bptr0 = W_fc + (size_t)(bn0 + srow) * ND + schunk;
    const float* bptr1 = W_fc + (size_t)(bn0 + 64 + srow) * ND + schunk;
    int frow = lane & 15, fk = (lane >> 4) * 8;
    f32x4 acc[8] = {};
    for (int kt = 0; kt < ND; kt += 32) {
        uint4 av = *reinterpret_cast<const uint4*>(aptr + kt);
        float4 c0 = *reinterpret_cast<const float4*>(bptr0 + kt);
        float4 c1 = *reinterpret_cast<const float4*>(bptr0 + kt + 4);
        float4 d0 = *reinterpret_cast<const float4*>(bptr1 + kt);
        float4 d1 = *reinterpret_cast<const float4*>(bptr1 + kt + 4);
        uint4 bv0, bv1;
        bv0.x = f2b(c0.x) | ((unsigned)f2b(c0.y) << 16);
        bv0.y = f2b(c0.z) | ((unsigned)f2b(c0.w) << 16);
        bv0.z = f2b(c1.x) | ((unsigned)f2b(c1.y) << 16);
        bv0.w = f2b(c1.z) | ((unsigned)f2b(c1.w) << 16);
        bv1.x = f2b(d0.x) | ((unsigned)f2b(d0.y) << 16);
        bv1.y = f2b(d0.z) | ((unsigned)f2b(d0.w) << 16);
        bv1.z = f2b(d1.x) | ((unsigned)f2b(d1.y) << 16);
        bv1.w = f2b(d1.z) | ((unsigned)f2b(d1.w) << 16);
        *reinterpret_cast<uint4*>(&As[srow][schunk]) = av;
        *reinterpret_cast<uint4*>(&Bs[srow][schunk]) = bv0;
        *reinterpret_cast<uint4*>(&Bs[64 + srow][schunk]) = bv1;
        __syncthreads();
        short8 af = *reinterpret_cast<const short8*>(&As[w * 16 + frow][fk]);
        #pragma unroll
        for (int nn = 0; nn < 8; ++nn) {
            short8 bf = *reinterpret_cast<const short8*>(&Bs[nn * 16 + frow][fk]);
            acc[nn] = __builtin_amdgcn_mfma_f32_16x16x32_bf16(af, bf, acc[nn], 0, 0, 0);
        }
        __syncthreads();
    }
    int rl0 = w * 16 + (lane >> 4) * 4;
    int ccol0 = lane & 15;
    #pragma unroll
    for (int i = 0; i < 4; ++i) {
        int rm = rowmap[bm0 + rl0 + i];
        if (rm < 0) continue;
        int t = rm / NB, b = rm % NB;
        float* orow = out + ((size_t)b * NT + t) * NV;
        #pragma unroll
        for (int nn = 0; nn < 8; ++nn) {
            int col = bn0 + nn * 16 + ccol0;
            orow[col] = acc[nn][i] + bias[col];
        }
    }
}

// ---------------- k_attg: attg[32][2560] = h @ [W_da;W_fb]^T + [b_da;b_fb] (40 blocks) ----------------
__global__ __launch_bounds__(256) void k_attg(
    const float* __restrict__ hc, const float* __restrict__ W_da, const float* __restrict__ W_fb,
    const float* __restrict__ b_da, const float* __restrict__ b_fb, float* __restrict__ attg)
{
    __shared__ float As[32][32];
    __shared__ float Ws[64][33];
    int n0 = blockIdx.x * 64;
    int tid = threadIdx.x;
    int lb = tid / 8, lkq = tid % 8;
    int b4 = (tid / 32) * 4, nl = (tid % 32) * 2;
    float acc[4][2] = {};
    for (int kt = 0; kt < 512; kt += 32) {
        float4 a4 = *reinterpret_cast<const float4*>(hc + (size_t)lb * 1024 + kt + lkq * 4);
        As[lkq * 4 + 0][lb] = a4.x; As[lkq * 4 + 1][lb] = a4.y;
        As[lkq * 4 + 2][lb] = a4.z; As[lkq * 4 + 3][lb] = a4.w;
        #pragma unroll
        for (int r = 0; r < 2; ++r) {
            int s = tid + r * 256;
            int n_l = s / 8, kq = s % 8;
            int ng = n0 + n_l;
            const float* wrow = (ng < 512) ? (W_da + (size_t)ng * 512)
                                           : (W_fb + (size_t)(ng - 512) * 512);
            float4 w4 = *reinterpret_cast<const float4*>(wrow + kt + kq * 4);
            Ws[n_l][kq * 4 + 0] = w4.x; Ws[n_l][kq * 4 + 1] = w4.y;
            Ws[n_l][kq * 4 + 2] = w4.z; Ws[n_l][kq * 4 + 3] = w4.w;
        }
        __syncthreads();
        #pragma unroll
        for (int k = 0; k < 32; ++k) {
            float4 av = *reinterpret_cast<const float4*>(&As[k][b4]);
            float w0 = Ws[nl][k], w1 = Ws[nl + 1][k];
            acc[0][0] += av.x * w0; acc[0][1] += av.x * w1;
            acc[1][0] += av.y * w0; acc[1][1] += av.y * w1;
            acc[2][0] += av.z * w0; acc[2][1] += av.z * w1;
            acc[3][0] += av.w * w0; acc[3][1] += av.w * w1;
        }
        __syncthreads();
    }
    #pragma unroll
    for (int j = 0; j < 2; ++j) {
        int ng = n0 + nl + j;
        float bias = (ng < 512) ? b_da[ng] : b_fb[ng - 512];
        #pragma unroll
        for (int i = 0; i < 4; ++i)
            attg[(size_t)(b4 + i) * 2560 + ng] = acc[i][j] + bias;
    }
}

// ---------------- k_e: e scores from bf16 att1 (grid 7 x 32) ----------------
__global__ __launch_bounds__(256) void k_e(
    const unsigned short* __restrict__ att1B, const float* __restrict__ attg,
    const float* __restrict__ w_fa, const float* __restrict__ b_fa,
    float* __restrict__ e)
{
    __shared__ float att2s[ND];
    __shared__ float wfas[ND];
    int b = blockIdx.y, tid = threadIdx.x;
    const float* ag = attg + (size_t)b * 2560;
    for (int d = tid; d < ND; d += 256) { att2s[d] = ag[d]; wfas[d] = w_fa[d]; }
    __syncthreads();
    int w = tid >> 6, lane = tid & 63;
    int p0 = blockIdx.x * 28;
    const unsigned short* a1 = att1B + ((size_t)b * NP + p0) * ND;
    #pragma unroll
    for (int i = 0; i < 7; ++i) {
        int p = w + 4 * i;
        const unsigned short* row = a1 + (size_t)p * ND;
        float s = 0.f;
        #pragma unroll
        for (int j = 0; j < 2; ++j) {
            int d = j * 256 + lane * 4;
            uint2 u = *reinterpret_cast<const uint2*>(row + d);   // 4 bf16
            float v0 = b2f_lo(u.x), v1 = b2f_hi(u.x);
            float v2 = b2f_lo(u.y), v3 = b2f_hi(u.y);
            float4 a2 = *reinterpret_cast<const float4*>(&att2s[d]);
            float4 wf = *reinterpret_cast<const float4*>(&wfas[d]);
            s += fmaxf(v0 + a2.x, 0.f) * wf.x + fmaxf(v1 + a2.y, 0.f) * wf.y
               + fmaxf(v2 + a2.z, 0.f) * wf.z + fmaxf(v3 + a2.w, 0.f) * wf.w;
        }
        for (int off = 32; off > 0; off >>= 1) s += __shfl_down(s, off);
        if (lane == 0) e[(size_t)b * NP + p0 + p] = s + b_fa[0];
    }
}

// ---------------- k_awe: softmax + awe + gate + xh (grid 8 x 32) ----------------
__global__ __launch_bounds__(256) void k_awe(
    const float* __restrict__ enc, const int* __restrict__ sind, const int* __restrict__ dlens,
    const int* __restrict__ caps, const float* __restrict__ emb_W,
    const float* __restrict__ e, const float* __restrict__ attg,
    float* __restrict__ xh, float* __restrict__ out_alpha, int t)
{
    __shared__ float es[256];
    __shared__ float red[256];
    int kc = blockIdx.x, b = blockIdx.y, tid = threadIdx.x;
    float ev = -1e30f;
    if (tid < NP) { float v = e[(size_t)b * NP + tid]; es[tid] = v; ev = v; }
    red[tid] = ev; __syncthreads();
    for (int s2 = 128; s2 > 0; s2 >>= 1) { if (tid < s2) red[tid] = fmaxf(red[tid], red[tid + s2]); __syncthreads(); }
    float m = red[0]; __syncthreads();
    float xe = (tid < NP) ? expf(es[tid] - m) : 0.f;
    red[tid] = xe; __syncthreads();
    for (int s2 = 128; s2 > 0; s2 >>= 1) { if (tid < s2) red[tid] += red[tid + s2]; __syncthreads(); }
    float inv = 1.0f / red[0];
    __syncthreads();
    es[tid] = xe * inv;
    __syncthreads();

    int k = kc * 256 + tid;
    const float* ec = enc + (size_t)sind[b] * NP * NE + k;
    float s0 = 0.f, s1 = 0.f, s2v = 0.f, s3 = 0.f;
    #pragma unroll 4
    for (int p = 0; p < NP; p += 4) {
        s0 += es[p + 0] * ec[(size_t)(p + 0) * NE];
        s1 += es[p + 1] * ec[(size_t)(p + 1) * NE];
        s2v += es[p + 2] * ec[(size_t)(p + 2) * NE];
        s3 += es[p + 3] * ec[(size_t)(p + 3) * NE];
    }
    float awe = (s0 + s1) + (s2v + s3);
    float gp = attg[(size_t)b * 2560 + 512 + k];      // includes b_fb
    float gate = 1.f / (1.f + expf(-gp));
    xh[(size_t)b * 3072 + 512 + k] = gate * awe;
    if (kc == 0) {
        bool live = (t < dlens[b]);
        if (tid < NP) out_alpha[((size_t)b * NT + t) * NP + tid] = live ? es[tid] : 0.f;
        const float* er = emb_W + (size_t)caps[sind[b] * NL + t] * ND;
        xh[(size_t)b * 3072 + tid] = er[tid];
        xh[(size_t)b * 3072 + 256 + tid] = er[256 + tid];
    }
}

// ---------------- k_gates: gates GEMM partials (128 blocks: 32 ntiles x 4 ksplit of 768) ----------------
__global__ __launch_bounds__(256) void k_gates(
    const float* __restrict__ xh, const float* __restrict__ W_ih, const float* __restrict__ W_hh,
    float* __restrict__ gpart)
{
    __shared__ float smem[3200];
    int blk = blockIdx.x, tid = threadIdx.x;
    int nt = blk & 31, ks = blk >> 5;
    float* As = smem;
    float (*Ws)[33] = (float(*)[33])(smem + 1024);
    int n0 = nt * 64;
    int lb = tid / 8, lkq = tid % 8;
    int b4 = (tid / 32) * 4, nl = (tid % 32) * 2;
    float acc[4][2] = {};
    for (int kt = ks * 768; kt < ks * 768 + 768; kt += 32) {
        float4 a4 = *reinterpret_cast<const float4*>(xh + (size_t)lb * 3072 + kt + lkq * 4);
        As[(lkq * 4 + 0) * 32 + lb] = a4.x; As[(lkq * 4 + 1) * 32 + lb] = a4.y;
        As[(lkq * 4 + 2) * 32 + lb] = a4.z; As[(lkq * 4 + 3) * 32 + lb] = a4.w;
        #pragma unroll
        for (int r = 0; r < 2; ++r) {
            int s = tid + r * 256;
            int n_l = s / 8, kq = s % 8;
            int ng = n0 + n_l;
            int kk = kt + kq * 4;
            const float* wrow = (kk < 2560) ? (W_ih + (size_t)ng * 2560 + kk)
                                            : (W_hh + (size_t)ng * 512 + (kk - 2560));
            float4 w4 = *reinterpret_cast<const float4*>(wrow);
            Ws[n_l][kq * 4 + 0] = w4.x; Ws[n_l][kq * 4 + 1] = w4.y;
            Ws[n_l][kq * 4 + 2] = w4.z; Ws[n_l][kq * 4 + 3] = w4.w;
        }
        __syncthreads();
        #pragma unroll
        for (int k = 0; k < 32; ++k) {
            float4 av = *reinterpret_cast<const float4*>(&As[k * 32 + b4]);
            float w0 = Ws[nl][k], w1 = Ws[nl + 1][k];
            acc[0][0] += av.x * w0; acc[0][1] += av.x * w1;
            acc[1][0] += av.y * w0; acc[1][1] += av.y * w1;
            acc[2][0] += av.z * w0; acc[2][1] += av.z * w1;
            acc[3][0] += av.w * w0; acc[3][1] += av.w * w1;
        }
        __syncthreads();
    }
    float* Cp = gpart + (size_t)ks * NB * 2048;
    #pragma unroll
    for (int j = 0; j < 2; ++j)
        #pragma unroll
        for (int i = 0; i < 4; ++i)
            Cp[(size_t)(b4 + i) * 2048 + n0 + nl + j] = acc[i][j];
}

// ---------------- k_cell: reduce partials + LSTM cell; hseq stored bf16 ----------------
__global__ __launch_bounds__(256) void k_cell(
    const float* __restrict__ gpart, const int* __restrict__ dlens,
    const float* __restrict__ b_ih, const float* __restrict__ b_hh,
    float* __restrict__ hc, unsigned short* __restrict__ hseqB, float* __restrict__ xh, int t)
{
    int b = blockIdx.x;
    for (int d = threadIdx.x; d < ND; d += 256) {
        float g0 = b_ih[d] + b_hh[d];
        float g1 = b_ih[512 + d] + b_hh[512 + d];
        float g2 = b_ih[1024 + d] + b_hh[1024 + d];
        float g3 = b_ih[1536 + d] + b_hh[1536 + d];
        #pragma unroll
        for (int ks = 0; ks < 4; ++ks) {
            const float* gp = gpart + ((size_t)ks * NB + b) * 2048;
            g0 += gp[d]; g1 += gp[512 + d]; g2 += gp[1024 + d]; g3 += gp[1536 + d];
        }
        float ig = 1.f / (1.f + expf(-g0));
        float fg = 1.f / (1.f + expf(-g1));
        float gt = tanhf(g2);
        float og = 1.f / (1.f + expf(-g3));
        float c_old = hc[(size_t)b * 1024 + 512 + d];
        float c_new = fg * c_old + ig * gt;
        float h_new = og * tanhf(c_new);
        hseqB[((size_t)t * NB + b) * ND + d] = f2b(h_new);
        if (t < dlens[b]) {
            hc[(size_t)b * 1024 + d] = h_new;
            hc[(size_t)b * 1024 + 512 + d] = c_new;
            xh[(size_t)b * 3072 + 2560 + d] = h_new;
        }
    }
}

// ---------------- launcher ----------------
extern "C" void kernel_launch(void* const* d_in, const int* in_sizes, int n_in,
                              void* d_out, int out_size, void* d_ws, size_t ws_size,
                              hipStream_t stream)
{
    const float* enc   = (const float*)d_in[0];
    const int*   caps  = (const int*)d_in[1];
    const int*   clens = (const int*)d_in[2];
    const float* emb_W = (const float*)d_in[3];
    const float* W_ea  = (const float*)d_in[4];
    const float* b_ea  = (const float*)d_in[5];
    const float* W_da  = (const float*)d_in[6];
    const float* b_da  = (const float*)d_in[7];
    const float* w_fa  = (const float*)d_in[8];
    const float* b_fa  = (const float*)d_in[9];
    const float* W_ih  = (const float*)d_in[10];
    const float* b_ih  = (const float*)d_in[11];
    const float* W_hh  = (const float*)d_in[12];
    const float* b_hh  = (const float*)d_in[13];
    const float* W_h0  = (const float*)d_in[14];
    const float* b_h0  = (const float*)d_in[15];
    const float* W_c0  = (const float*)d_in[16];
    const float* b_c0  = (const float*)d_in[17];
    const float* W_fb  = (const float*)d_in[18];
    const float* b_fb  = (const float*)d_in[19];
    const float* W_fc  = (const float*)d_in[20];
    const float* b_fc  = (const float*)d_in[21];

    float* out = (float*)d_out;
    float* out_alpha = out + (size_t)NB * NT * NV;

    int* iws    = (int*)d_ws;
    int* sind   = iws;
    int* dlens  = iws + 32;
    int* rowmap = iws + 64;
    int* mpad   = iws + 704;
    float* base = (float*)d_ws + 1024;
    float* mean_enc = base;                         // 65536
    float* hc    = mean_enc + NB * NE;              // 32768
    float* attg  = hc + NB * 1024;                  // 81920
    float* xh    = attg + NB * 2560;                // 98304
    float* e     = xh + NB * 3072;                  // 6272
    float* gpart = e + NB * NP;                     // 262144 (also spart for setup: 8*32*1024)
    unsigned short* att1B = (unsigned short*)(gpart + 4 * NB * 2048);   // 6272*512 bf16
    unsigned short* hseqB = att1B + (size_t)NB * NP * ND;               // 640*512 bf16

    k_sort<<<1, 64, 0, stream>>>(clens, sind, dlens, rowmap, mpad);
    k_zero<<<NB * NT, 256, 0, stream>>>(dlens, out);
    k_mean<<<dim3(NE / 256, NB), 256, 0, stream>>>(enc, sind, mean_enc);
    gemm_skinny_split<<<dim3(16, 8), 256, 0, stream>>>(mean_enc, W_h0, W_c0, gpart);
    k_hc0<<<dim3(NB), 256, 0, stream>>>(gpart, b_h0, b_c0, hc, xh);
    gemm_att1_mfma<<<dim3(832), 256, 0, stream>>>(enc, W_ea, b_ea, att1B, sind);

    for (int t = 0; t < NT; ++t) {
        k_attg<<<dim3(40), 256, 0, stream>>>(hc, W_da, W_fb, b_da, b_fb, attg);
        k_e<<<dim3(7, NB), 256, 0, stream>>>(att1B, attg, w_fa, b_fa, e);
        k_awe<<<dim3(8, NB), 256, 0, stream>>>(enc, sind, dlens, caps, emb_W,
                                               e, attg, xh, out_alpha, t);
        k_gates<<<dim3(128), 256, 0, stream>>>(xh, W_ih, W_hh, gpart);
        k_cell<<<dim3(NB), 256, 0, stream>>>(gpart, dlens, b_ih, b_hh, hc, hseqB, xh, t);
    }

    gemm_preds_mfma<<<dim3(2560), 256, 0, stream>>>(hseqB, W_fc, b_fc, out, rowmap, mpad);
}